// Round 3
// baseline (1447.416 us; speedup 1.0000x reference)
//
#include <hip/hip_runtime.h>

// BioRNN fp32: T=1000, B=4096, H=50, IN=8, OUT=6.
//   r = relu(h);  y_t = r@W_out^T + b_out;  h += DT*(-h + x@W_in^T + r@W_rec^T + bias)
//
// Wave-local K-split design, NO barriers:
//   block = 64 threads = 1 wave; grid = 1024 (4 batches per wave).
//   lane = ks (bit0) + 2*jg (bits1-3) + 16*b (bits4-5):
//     b  = batch slot (4/wave), jg = row group (8), ks = K-half (2).
//   Each lane owns 7 rows {jg+8m, m=0..6}; m=6 row 48+jg: hidden for jg<2,
//   y-output row jg-2 for jg>=2. Each lane covers K-slots [32ks, 32ks+32) of
//   a 64-slot K-vector: slots 0..49 = r, 50..51 = 0, 52..59 = x, 60..63 = 0.
//   => 224 weight floats/lane in VGPRs, 8 ds_read_b128/lane/step (vs 13 for
//   full-K), and all r-exchange is within ONE wave -> no __syncthreads, only
//   in-order DS + lgkmcnt. K-half partial sums combined with v_mov_dpp
//   quad_perm(1,0,3,2) (lane^1) on the VALU pipe.
//
// amdgpu_waves_per_eu(1,1) pins occupancy to 1 wave/SIMD (512-VGPR budget):
// round-2 failure was the allocator targeting 2 waves/EU (VGPR=180) and
// spilling the 208-float weight array. ~300 VGPRs must stay resident.

#define T_STEPS 1000
#define BATCH   4096
#define INSZ    8
#define H       50
#define OUTSZ   6
#define DT      0.1f
#define BPW     4          // batches per wave
#define KSLOT   68         // padded K stride in floats (68*4B: b128-aligned, banks spread)
#define NM      7          // rows per lane

__device__ __forceinline__ float dpp_xor1_add(float x) {
    // acc + partner(lane^1) via quad_perm [1,0,3,2] = 0xB1
    int i = __builtin_bit_cast(int, x);
    int j = __builtin_amdgcn_mov_dpp(i, 0xB1, 0xF, 0xF, true);
    return x + __builtin_bit_cast(float, j);
}

__global__ __attribute__((amdgpu_waves_per_eu(1, 1))) __launch_bounds__(64)
void biornn_kernel(const float* __restrict__ xg,   // (T, B, INSZ)
                   const float* __restrict__ Wi,   // (H, INSZ)
                   const float* __restrict__ Wr,   // (H, H)
                   const float* __restrict__ bs,   // (H)
                   const float* __restrict__ Wo,   // (OUTSZ, H)
                   const float* __restrict__ bo,   // (OUTSZ)
                   float* __restrict__ out)        // (T, B, OUTSZ)
{
    __shared__ __align__(16) float plane[BPW][KSLOT];
    float* const psh = (float*)plane;

    const int lane = threadIdx.x;          // 0..63 (one wave)
    const int ks   = lane & 1;             // K-half
    const int jg   = (lane >> 1) & 7;      // row group
    const int b    = lane >> 4;            // batch slot
    const int bg   = blockIdx.x * BPW + b; // global batch
    const int pb   = b * KSLOT;

    // ---- per-lane rows ----
    int rows[NM];
#pragma unroll
    for (int m = 0; m < NM; ++m) rows[m] = jg + 8 * m;   // m=6 -> 48+jg

    // ---- weights into registers (one-time, branchy is fine) ----
    // slot i of this lane's K-half: k = 32*ks + i
    float w[NM][32];
#pragma unroll
    for (int m = 0; m < NM; ++m) {
        const int row = rows[m];
#pragma unroll
        for (int i = 0; i < 32; ++i) {
            const int k = 32 * ks + i;
            float v = 0.f;
            if (k < H)
                v = (row < H) ? Wr[row * H + k] : Wo[(row - H) * H + k];
            else if (k >= 52 && k < 60)
                v = (row < H) ? Wi[row * INSZ + (k - 52)] : 0.f;  // y-rows: no x term
            w[m][i] = v;
        }
    }
    float biasv[NM];
#pragma unroll
    for (int m = 0; m < NM; ++m) {
        const int row = rows[m];
        biasv[m] = ks ? 0.f : ((row < H) ? bs[row] : bo[row - H]);  // only ks=0 adds bias
    }

    // ---- zero the never-rewritten K-slots (50,51,60..67): LDS is undefined ----
    {
        const int s = lane & 15;
        if (s < 2) plane[b][50 + s] = 0.f;
        if (s < 8) plane[b][60 + s] = 0.f;
    }

    // ---- per-step LDS write slots (4 uniform ds_write_b32 per lane) ----
    // ks=0 publishes rows m=0..3; ks=1 publishes m=4,5,6(+dummy).
    const int ws0 = pb + (ks ? jg + 32 : jg);
    const int ws1 = ws0 + 8;
    const int ws2 = pb + (ks ? ((jg < 2) ? 48 + jg : 62) : jg + 16);  // 62 = trash (w=0)
    const int ws3 = pb + (ks ? 63 : jg + 24);                          // 63 = trash (w=0)

    // ---- x prefetch: lanes with (lane&15)==0 own x[bg] ----
    const float* xp = xg + (size_t)bg * INSZ;
    float4 xa = make_float4(0.f, 0.f, 0.f, 0.f), xb = xa;
    if ((lane & 15) == 0) {
        xa = *(const float4*)xp;
        xb = *(const float4*)(xp + 4);
    }
    xp += (size_t)BATCH * INSZ;
    float4* const xq = (float4*)(psh + pb + 52);   // slots 52..59

    // ---- y pointer (deref only when ks==0 && jg>=2) ----
    float* yp = out + (size_t)bg * OUTSZ + ((jg >= 2) ? (jg - 2) : 0);

    const float4* const kp = (const float4*)(psh + pb + 32 * ks);

    float h[NM];
#pragma unroll
    for (int m = 0; m < NM; ++m) h[m] = 0.f;

#pragma unroll 1
    for (int t = 0; t < T_STEPS; ++t) {
        // publish r = relu(h) (4 uniform b32 writes) + x_t (2 b128, masked)
        float rr[NM];
#pragma unroll
        for (int m = 0; m < NM; ++m) rr[m] = fmaxf(h[m], 0.f);
        psh[ws0] = ks ? rr[4] : rr[0];
        psh[ws1] = ks ? rr[5] : rr[1];
        psh[ws2] = ks ? rr[6] : rr[2];
        psh[ws3] = ks ? rr[6] : rr[3];
        if ((lane & 15) == 0) { xq[0] = xa; xq[1] = xb; }
        asm volatile("" ::: "memory");   // keep DS writes before DS reads (in-order pipe does the rest)

        // read this lane's K-half (8 x ds_read_b128)
        float4 kv[8];
#pragma unroll
        for (int i = 0; i < 8; ++i) kv[i] = kp[i];

        // 7 rows x 32 slots of FMA (x-term and zero-pads included uniformly)
        float acc[NM];
#pragma unroll
        for (int m = 0; m < NM; ++m) acc[m] = biasv[m];
#pragma unroll
        for (int i = 0; i < 8; ++i) {
#pragma unroll
            for (int m = 0; m < NM; ++m) {
                acc[m] = fmaf(kv[i].x, w[m][4 * i + 0], acc[m]);
                acc[m] = fmaf(kv[i].y, w[m][4 * i + 1], acc[m]);
                acc[m] = fmaf(kv[i].z, w[m][4 * i + 2], acc[m]);
                acc[m] = fmaf(kv[i].w, w[m][4 * i + 3], acc[m]);
            }
        }

        // combine K-halves (lane^1) on the VALU pipe
#pragma unroll
        for (int m = 0; m < NM; ++m) acc[m] = dpp_xor1_add(acc[m]);

        // prefetch x[t+1]
        if (t + 1 < T_STEPS) {
            if ((lane & 15) == 0) {
                xa = *(const float4*)xp;
                xb = *(const float4*)(xp + 4);
            }
            xp += (size_t)BATCH * INSZ;
        }

        // h <- h + DT*(acc - h)   (garbage-but-bounded on y rows, unused)
#pragma unroll
        for (int m = 0; m < NM; ++m) h[m] = fmaf(DT, acc[m] - h[m], h[m]);

        // y_t for rows 50..55 (bias already folded via biasv)
        if (ks == 0 && jg >= 2) *yp = acc[6];
        yp += BATCH * OUTSZ;
    }
}

extern "C" void kernel_launch(void* const* d_in, const int* in_sizes, int n_in,
                              void* d_out, int out_size, void* d_ws, size_t ws_size,
                              hipStream_t stream)
{
    const float* xg = (const float*)d_in[0];  // input_seq (1000,4096,8)
    const float* Wi = (const float*)d_in[1];  // W_in (50,8)
    const float* Wr = (const float*)d_in[2];  // W_rec (50,50)
    const float* bs = (const float*)d_in[3];  // bias (50)
    const float* Wo = (const float*)d_in[4];  // W_out_w (6,50)
    const float* bo = (const float*)d_in[5];  // W_out_b (6)
    float* outp = (float*)d_out;              // (1000,4096,6)

    dim3 grid(BATCH / BPW);   // 1024 one-wave blocks -> 4 waves/CU, 1/SIMD
    dim3 block(64);
    hipLaunchKernelGGL(biornn_kernel, grid, block, 0, stream,
                       xg, Wi, Wr, bs, Wo, bo, outp);
}